// Round 11
// baseline (188.119 us; speedup 1.0000x reference)
//
#include <hip/hip_runtime.h>
#include <cstdint>
#include <cstddef>

typedef unsigned short u16;
typedef __bf16 bf16x8 __attribute__((ext_vector_type(8)));
typedef float    f32x4 __attribute__((ext_vector_type(4)));
typedef unsigned int u32x4 __attribute__((ext_vector_type(4)));
typedef unsigned short u16x4 __attribute__((ext_vector_type(4)));

// ---------- problem constants ----------
constexpr int BB   = 16;
constexpr int NN   = 2048;
constexpr int SS   = 512;
constexpr int DD   = 384;   // D1 = D2 = 384
constexpr int CIN  = 768;   // D1+D2
constexpr int HID  = 768;
constexpr int OUTC = 384;
constexpr int MROWS = BB * NN; // 32768
constexpr float KNN_EPS = 1.1920929e-07f; // finfo(f32).eps
constexpr float BN_EPS  = 1e-5f;

// ---------- workspace layout (bytes) ----------
constexpr size_t OFF_W0B  = 0;                              // 768*768 bf16
constexpr size_t OFF_W1B  = OFF_W0B  + (size_t)HID*CIN*2;   // 384*768 bf16
constexpr size_t OFF_IDX  = OFF_W1B  + (size_t)OUTC*HID*2;  // MROWS*5 int
constexpr size_t OFF_WGT  = OFF_IDX  + (size_t)MROWS*5*4;
constexpr size_t OFF_SUM1 = OFF_WGT  + (size_t)MROWS*5*4;   // 768*2 f32
constexpr size_t OFF_SUM2 = OFF_SUM1 + (size_t)HID*2*4;     // 384*2 f32
constexpr size_t OFF_XCAT = OFF_SUM2 + (size_t)OUTC*2*4;    // MROWS*768 bf16 (reused as ybf)
constexpr size_t OFF_H1   = OFF_XCAT + (size_t)MROWS*CIN*2; // MROWS*768 bf16
constexpr size_t OFF_P2B  = OFF_H1   + (size_t)MROWS*HID*2; // 16*512*384 bf16 (optional)
constexpr size_t NEED_P2B = OFF_P2B  + (size_t)BB*SS*DD*2;

// ---------- helpers ----------
__device__ inline float bf2f(u16 u){ unsigned int i = ((unsigned int)u)<<16; float f; __builtin_memcpy(&f,&i,4); return f; }
__device__ inline u16 f2bf(float f){ unsigned int x; __builtin_memcpy(&x,&f,4);
  unsigned int r = (x + 0x7fffu + ((x>>16)&1u)) >> 16; return (u16)r; }

__device__ inline void async16(const void* g, void* l){
  __builtin_amdgcn_global_load_lds((const __attribute__((address_space(1))) void*)g,
                                   (__attribute__((address_space(3))) void*)l, 16, 0, 0);
}

// ---------- W f32 -> bf16, optional p2 -> bf16, zero stats ----------
__global__ void cvtw_kernel(const float* __restrict__ W0, const float* __restrict__ W1,
                            const float* __restrict__ p2,
                            u16* __restrict__ W0b, u16* __restrict__ W1b,
                            u16* __restrict__ p2b, float* __restrict__ sums){
  int t = blockIdx.x*256 + threadIdx.x;
  if (t < HID*CIN)  W0b[t] = f2bf(W0[t]);
  if (t < OUTC*HID) W1b[t] = f2bf(W1[t]);
  if (p2b != nullptr && t < BB*SS*DD) p2b[t] = f2bf(p2[t]);
  if (t < (HID + OUTC)*2) sums[t] = 0.f;
}

// ---------- KNN: one wave per query ----------
__global__ __launch_bounds__(256) void knn_kernel(const float* __restrict__ xyz1,
                                                  const float* __restrict__ xyz2,
                                                  const int* __restrict__ elens,
                                                  int* __restrict__ idxO, float* __restrict__ wO){
  __shared__ f32x4 sp[SS];
  const int tid = threadIdx.x;
  const int wv = tid >> 6, lane = tid & 63;
  const int wg = blockIdx.x*4 + wv;       // global wave id = query id
  const int b = wg >> 11;                 // 2048 queries per batch
  const int n = wg & (NN-1);
  for (int s = tid; s < SS; s += 256){
    float x = xyz2[((size_t)b*SS + s)*3 + 0];
    float y = xyz2[((size_t)b*SS + s)*3 + 1];
    float z = xyz2[((size_t)b*SS + s)*3 + 2];
    f32x4 v; v[0]=x; v[1]=y; v[2]=z; v[3]=x*x+y*y+z*z;
    sp[s]=v;
  }
  __syncthreads();
  const size_t qoff = ((size_t)b*NN + n)*3;
  const float qx = xyz1[qoff+0], qy = xyz1[qoff+1], qz = xyz1[qoff+2];
  const float qq = qx*qx + qy*qy + qz*qz;
  const int Sl = elens[b];

  float d0=1e30f,d1=1e30f,d2v=1e30f,d3=1e30f,d4=1e30f;
  int   i0=0,i1=0,i2=0,i3=0,i4=0;
  #pragma unroll
  for (int j=0;j<8;j++){
    const int s = lane + j*64;
    f32x4 v = sp[s];
    float d = (s < Sl) ? (qq + v[3] - 2.f*(qx*v[0] + qy*v[1] + qz*v[2])) : 1e30f;
    bool lt4=d<d4, lt3=d<d3, lt2=d<d2v, lt1=d<d1, lt0=d<d0;
    float nd4 = lt3 ? d3 : (lt4 ? d : d4); int ni4 = lt3 ? i3 : (lt4 ? s : i4);
    float nd3 = lt2 ? d2v: (lt3 ? d : d3); int ni3 = lt2 ? i2 : (lt3 ? s : i3);
    float nd2 = lt1 ? d1 : (lt2 ? d : d2v);int ni2 = lt1 ? i1 : (lt2 ? s : i2);
    float nd1 = lt0 ? d0 : (lt1 ? d : d1); int ni1 = lt0 ? i0 : (lt1 ? s : i1);
    float nd0 = lt0 ? d  : d0;             int ni0 = lt0 ? s  : i0;
    d4=nd4;i4=ni4; d3=nd3;i3=ni3; d2v=nd2;i2=ni2; d1=nd1;i1=ni1; d0=nd0;i0=ni0;
  }
  float outd[5]; int outi[5];
  #pragma unroll
  for (int r=0;r<5;r++){
    float bd = d0; int bs = i0;
    #pragma unroll
    for (int m=1;m<64;m<<=1){
      float od = __shfl_xor(bd, m, 64);
      int   os = __shfl_xor(bs, m, 64);
      if (od < bd || (od == bd && os < bs)){ bd = od; bs = os; }
    }
    outd[r]=bd; outi[r]=bs;
    if (d0 == bd && i0 == bs){ d0=d1;i0=i1; d1=d2v;i1=i2; d2v=d3;i2=i3; d3=d4;i3=i4; d4=1e30f;i4=0; }
  }
  if (lane == 0){
    float r0=1.f/(outd[0]+KNN_EPS), r1=1.f/(outd[1]+KNN_EPS), r2=1.f/(outd[2]+KNN_EPS),
          r3=1.f/(outd[3]+KNN_EPS), r4=1.f/(outd[4]+KNN_EPS);
    float inv = 1.f/(r0+r1+r2+r3+r4);
    size_t base = (size_t)wg*5;
    idxO[base+0]=outi[0]; idxO[base+1]=outi[1]; idxO[base+2]=outi[2]; idxO[base+3]=outi[3]; idxO[base+4]=outi[4];
    wO[base+0]=r0*inv; wO[base+1]=r1*inv; wO[base+2]=r2*inv; wO[base+3]=r3*inv; wO[base+4]=r4*inv;
  }
}

// ---------- xcat: 4 rows/block, 96 threads/row; gathers bf16 p2b (or f32 p2) ----------
template<bool BF16G>
__global__ __launch_bounds__(384) void xcat_kernel(const float* __restrict__ p1,
                                                   const float* __restrict__ p2,
                                                   const u16* __restrict__ p2b,
                                                   const int* __restrict__ idx,
                                                   const float* __restrict__ wgt,
                                                   u16* __restrict__ xcat){
  const int t = threadIdx.x;
  const int rloc = t / 96, c4 = t % 96;
  const int row = blockIdx.x*4 + rloc;
  const int b = row >> 11;
  const int c = c4*4;
  f32x4 v1 = *reinterpret_cast<const f32x4*>(p1 + (size_t)row*DD + c);
  size_t ib = (size_t)row*5;
  f32x4 acc = {0.f,0.f,0.f,0.f};
  #pragma unroll
  for (int k=0;k<5;k++){
    int id = idx[ib+k]; float w = wgt[ib+k];
    if (BF16G){
      u16x4 g = *reinterpret_cast<const u16x4*>(p2b + ((size_t)b*SS + id)*DD + c);
      #pragma unroll
      for (int j=0;j<4;j++) acc[j] += w * bf2f(g[j]);
    } else {
      f32x4 g = *reinterpret_cast<const f32x4*>(p2 + ((size_t)b*SS + id)*DD + c);
      #pragma unroll
      for (int j=0;j<4;j++) acc[j] += w * g[j];
    }
  }
  u16x4 o1, o2;
  #pragma unroll
  for (int j=0;j<4;j++){ o1[j] = f2bf(v1[j]); o2[j] = f2bf(acc[j]); }
  *reinterpret_cast<u16x4*>(xcat + (size_t)row*CIN + c)      = o1;
  *reinterpret_cast<u16x4*>(xcat + (size_t)row*CIN + DD + c) = o2;
}

// ---------- GEMM1 (R10 champion, 8-wave phase-split, unchanged) ----------
__global__ __launch_bounds__(512, 6) void gemm1_kernel(const u16* __restrict__ A,
                                                       const u16* __restrict__ Bw,
                                                       u16* __restrict__ Cout,
                                                       const int* __restrict__ plen,
                                                       float* __restrict__ sums){
  constexpr int K   = CIN;         // 768
  constexpr int NC  = HID;         // 768
  constexpr int GX  = NC/128;      // 6
  constexpr int NT  = K/32;        // 24
  constexpr int NWG = GX*256;      // 1536
  constexpr int CPX = NWG/8;
  __shared__ u16 Ash[2][128*32];
  __shared__ u16 Bsh[2][128*32];
  const int tid  = threadIdx.x;
  const int lane = tid & 63, wv = tid >> 6;    // 8 waves
  const int wr = wv >> 2, wc = wv & 3;         // 2 x 4 wave grid, per-wave 64x32
  const int l15 = lane & 15, l16 = lane >> 4;
  const int swz = (l15 >> 1) & 3;

  const int logical = (blockIdx.x & 7)*CPX + (blockIdx.x >> 3);
  const int bn = logical % GX, bm = logical / GX;

  const int srow = tid >> 2;
  const int sk4  = (tid & 3) ^ ((tid >> 3) & 3);
  const u16* gA = A  + (size_t)(bm*128 + srow)*K + sk4*8;
  const u16* gB = Bw + (size_t)(bn*128 + srow)*K + sk4*8;
  const int dst = (wv*64)*16;

  auto stageA = [&](int tt, int bi){ async16(gA + tt*32, (char*)&Ash[bi][0] + dst); };
  auto stageB = [&](int tt, int bi){ async16(gB + tt*32, (char*)&Bsh[bi][0] + dst); };

  int aoff[4], boff[2];
  #pragma unroll
  for (int m=0;m<4;m++) aoff[m] = (wr*64 + m*16 + l15)*32 + ((l16 ^ swz) << 3);
  #pragma unroll
  for (int n=0;n<2;n++) boff[n] = (wc*32 + n*16 + l15)*32 + ((l16 ^ swz) << 3);

  f32x4 acc[4][2] = {};

  stageA(0,0); stageB(0,0); stageA(1,1); stageB(1,1);
  asm volatile("s_waitcnt vmcnt(2)" ::: "memory");
  __builtin_amdgcn_s_barrier();
  __builtin_amdgcn_sched_barrier(0);

  for (int t=0; t<NT; ++t){
    const int cur = t & 1;
    const int tt = (t+2 < NT) ? (t+2) : (NT-1);
    bf16x8 af0 = *reinterpret_cast<const bf16x8*>(&Ash[cur][aoff[0]]);
    bf16x8 af1 = *reinterpret_cast<const bf16x8*>(&Ash[cur][aoff[1]]);
    bf16x8 af2 = *reinterpret_cast<const bf16x8*>(&Ash[cur][aoff[2]]);
    bf16x8 af3 = *reinterpret_cast<const bf16x8*>(&Ash[cur][aoff[3]]);
    bf16x8 bv0 = *reinterpret_cast<const bf16x8*>(&Bsh[cur][boff[0]]);
    asm volatile("s_waitcnt lgkmcnt(0)" ::: "memory");
    __builtin_amdgcn_s_barrier();
    __builtin_amdgcn_sched_barrier(0);
    stageA(tt, cur);
    __builtin_amdgcn_s_setprio(1);
    acc[0][0] = __builtin_amdgcn_mfma_f32_16x16x32_bf16(af0, bv0, acc[0][0], 0,0,0);
    acc[1][0] = __builtin_amdgcn_mfma_f32_16x16x32_bf16(af1, bv0, acc[1][0], 0,0,0);
    acc[2][0] = __builtin_amdgcn_mfma_f32_16x16x32_bf16(af2, bv0, acc[2][0], 0,0,0);
    acc[3][0] = __builtin_amdgcn_mfma_f32_16x16x32_bf16(af3, bv0, acc[3][0], 0,0,0);
    __builtin_amdgcn_s_setprio(0);
    bf16x8 bv1 = *reinterpret_cast<const bf16x8*>(&Bsh[cur][boff[1]]);
    asm volatile("s_waitcnt lgkmcnt(0)" ::: "memory");
    __builtin_amdgcn_s_barrier();
    __builtin_amdgcn_sched_barrier(0);
    stageB(tt, cur);
    __builtin_amdgcn_s_setprio(1);
    acc[0][1] = __builtin_amdgcn_mfma_f32_16x16x32_bf16(af0, bv1, acc[0][1], 0,0,0);
    acc[1][1] = __builtin_amdgcn_mfma_f32_16x16x32_bf16(af1, bv1, acc[1][1], 0,0,0);
    acc[2][1] = __builtin_amdgcn_mfma_f32_16x16x32_bf16(af2, bv1, acc[2][1], 0,0,0);
    acc[3][1] = __builtin_amdgcn_mfma_f32_16x16x32_bf16(af3, bv1, acc[3][1], 0,0,0);
    __builtin_amdgcn_s_setprio(0);
    asm volatile("s_waitcnt vmcnt(2)" ::: "memory");
    __builtin_amdgcn_s_barrier();
    __builtin_amdgcn_sched_barrier(0);
  }
  asm volatile("s_waitcnt vmcnt(0)" ::: "memory");
  __syncthreads();

  #pragma unroll
  for (int m=0;m<4;m++){
    int r0 = bm*128 + wr*64 + m*16 + l16*4;
    #pragma unroll
    for (int n=0;n<2;n++){
      int c = bn*128 + wc*32 + n*16 + l15;
      #pragma unroll
      for (int r=0;r<4;r++)
        Cout[(size_t)(r0+r)*NC + c] = f2bf(acc[m][n][r]);
    }
  }

  const int pl = plen[bm >> 4];
  const int rbase = (bm & 15)*128 + wr*64 + l16*4;
  float cs[2] = {0.f,0.f}, cs2[2] = {0.f,0.f};
  #pragma unroll
  for (int m=0;m<4;m++){
    #pragma unroll
    for (int r=0;r<4;r++){
      if (rbase + m*16 + r < pl){
        #pragma unroll
        for (int n=0;n<2;n++){
          float v = acc[m][n][r];
          cs[n] += v; cs2[n] += v*v;
        }
      }
    }
  }
  #pragma unroll
  for (int n=0;n<2;n++){
    cs[n]  += __shfl_xor(cs[n], 16, 64);  cs[n]  += __shfl_xor(cs[n], 32, 64);
    cs2[n] += __shfl_xor(cs2[n], 16, 64); cs2[n] += __shfl_xor(cs2[n], 32, 64);
  }
  float* lsum = (float*)&Ash[0][0];
  if (tid < 256) lsum[tid] = 0.f;
  __syncthreads();
  if (l16 == 0){
    #pragma unroll
    for (int n=0;n<2;n++){
      int col = wc*32 + n*16 + l15;
      atomicAdd(&lsum[col], cs[n]);
      atomicAdd(&lsum[128 + col], cs2[n]);
    }
  }
  __syncthreads();
  if (tid < 128)       atomicAdd(&sums[bn*128 + tid], lsum[tid]);
  else if (tid < 256)  atomicAdd(&sums[NC + bn*128 + (tid-128)], lsum[tid]);
}

// ---------- GEMM2: ring-buffered, coef1 computed in-block, BN1+ReLU fused on A, bf16 out ----------
__global__ __launch_bounds__(256) void gemm2_kernel(const u16* __restrict__ A,
                                                    const u16* __restrict__ Bw,
                                                    u16* __restrict__ Yout,
                                                    const int* __restrict__ plen,
                                                    float* __restrict__ sums,
                                                    const float* __restrict__ sum1,
                                                    const float* __restrict__ g0,
                                                    const float* __restrict__ b0){
  constexpr int GX = 3;
  constexpr int K  = HID;
  constexpr int NC = GX*128;       // 384
  constexpr int NSTEP = K/32;      // 24
  constexpr int NWG = GX*256;
  constexpr int CPX = NWG/8;
  __shared__ u16 As[2][128*32];
  __shared__ u16 Bs[3][128*32];
  __shared__ float cfl[HID*2];
  const int tid  = threadIdx.x;
  const int lane = tid & 63, wv = tid >> 6;
  const int wr = wv >> 1, wc = wv & 1;
  const int l15 = lane & 15, l16 = lane >> 4;
  const int sw  = (l15 >> 1) & 3;

  const int logical = (blockIdx.x & 7)*CPX + (blockIdx.x >> 3);
  const int bn = logical % GX, bm = logical / GX;

  int c8S[2], ldso[2];
  const u16* Ab[2]; const u16* Bb[2];
  #pragma unroll
  for (int j=0;j<2;j++){
    int ch = j*256 + wv*64 + lane;
    int row = ch >> 2;
    int c8 = (ch & 3) ^ ((ch >> 3) & 3);
    c8S[j] = c8;
    ldso[j] = (j*256 + wv*64)*16;
    Ab[j] = A  + (size_t)(bm*128 + row)*K + c8*8;
    Bb[j] = Bw + (size_t)(bn*128 + row)*K + c8*8;
  }

  auto stageB = [&](int nb, int kt){
    #pragma unroll
    for (int j=0;j<2;j++) async16(Bb[j] + kt*32, (char*)&Bs[nb][0] + ldso[j]);
  };
  u32x4 hv0, hv1;
  auto loadA = [&](int kt){
    hv0 = *reinterpret_cast<const u32x4*>(Ab[0] + kt*32);
    hv1 = *reinterpret_cast<const u32x4*>(Ab[1] + kt*32);
  };
  auto bnwrite = [&](int nb, int kt){
    #pragma unroll
    for (int j=0;j<2;j++){
      const int k0 = kt*32 + c8S[j]*8;
      float av[8], bv[8];
      *reinterpret_cast<f32x4*>(av)   = *reinterpret_cast<const f32x4*>(cfl + k0);
      *reinterpret_cast<f32x4*>(av+4) = *reinterpret_cast<const f32x4*>(cfl + k0 + 4);
      *reinterpret_cast<f32x4*>(bv)   = *reinterpret_cast<const f32x4*>(cfl + K + k0);
      *reinterpret_cast<f32x4*>(bv+4) = *reinterpret_cast<const f32x4*>(cfl + K + k0 + 4);
      u32x4 v = j ? hv1 : hv0; u32x4 o;
      #pragma unroll
      for (int q=0;q<4;q++){
        float lo = bf2f((u16)(v[q] & 0xffffu));
        float hi = bf2f((u16)(v[q] >> 16));
        lo = fmaxf(lo*av[2*q]   + bv[2*q],   0.f);
        hi = fmaxf(hi*av[2*q+1] + bv[2*q+1], 0.f);
        o[q] = (unsigned int)f2bf(lo) | ((unsigned int)f2bf(hi) << 16);
      }
      *reinterpret_cast<u32x4*>((char*)&As[nb][0] + ldso[j] + lane*16) = o;
    }
  };

  f32x4 acc[4][4] = {};

  // issue tile-0 loads, then compute coef1 into LDS while DMA is in flight
  loadA(0);
  __builtin_amdgcn_sched_barrier(0);
  stageB(0, 0); stageB(1, 1);
  {
    float cnt = 0.f;
    #pragma unroll
    for (int b=0;b<BB;b++) cnt += (float)plen[b];
    const float icnt = 1.f / cnt;
    for (int c = tid; c < HID; c += 256){
      float mean = sum1[c] * icnt;
      float var  = fmaxf(sum1[HID + c]*icnt - mean*mean, 0.f);
      float a = g0[c] * rsqrtf(var + BN_EPS);
      cfl[c] = a;
      cfl[HID + c] = b0[c] - mean*a;
    }
  }
  __syncthreads();
  bnwrite(0, 0);
  asm volatile("s_waitcnt vmcnt(2) lgkmcnt(0)" ::: "memory");
  __builtin_amdgcn_s_barrier();

  int rb = 0, wb = 2;
  for (int kt=0; kt<NSTEP; ++kt){
    const bool pf1 = (kt+1 < NSTEP), pf2 = (kt+2 < NSTEP);
    if (pf1) loadA(kt+1);
    __builtin_amdgcn_sched_barrier(0);
    if (pf2) stageB(wb, kt+2);

    bf16x8 af[4], bfr[4];
    const int aslot = kt & 1;
    #pragma unroll
    for (int m=0;m<4;m++){
      int r = wr*64 + m*16 + l15;
      af[m] = *reinterpret_cast<const bf16x8*>(&As[aslot][r*32 + ((l16 ^ sw) << 3)]);
    }
    #pragma unroll
    for (int n=0;n<4;n++){
      int c = wc*64 + n*16 + l15;
      bfr[n] = *reinterpret_cast<const bf16x8*>(&Bs[rb][c*32 + ((l16 ^ sw) << 3)]);
    }
    #pragma unroll
    for (int m=0;m<4;m++)
      #pragma unroll
      for (int n=0;n<4;n++)
        acc[m][n] = __builtin_amdgcn_mfma_f32_16x16x32_bf16(af[m], bfr[n], acc[m][n], 0, 0, 0);

    if (pf1) bnwrite((kt+1)&1, kt+1);

    if (pf1){
      if (pf2) asm volatile("s_waitcnt vmcnt(2) lgkmcnt(0)" ::: "memory");
      else     asm volatile("s_waitcnt vmcnt(0) lgkmcnt(0)" ::: "memory");
      __builtin_amdgcn_s_barrier();
    }
    rb = (rb==2) ? 0 : rb+1;
    wb = (wb==2) ? 0 : wb+1;
  }

  // ---- C write (bf16 y) ----
  #pragma unroll
  for (int m=0;m<4;m++){
    int r0 = bm*128 + wr*64 + m*16 + l16*4;
    #pragma unroll
    for (int n=0;n<4;n++){
      int c = bn*128 + wc*64 + n*16 + l15;
      #pragma unroll
      for (int r=0;r<4;r++)
        Yout[(size_t)(r0+r)*NC + c] = f2bf(acc[m][n][r]);
    }
  }

  // ---- masked stats (f32-exact) ----
  const int pl = plen[bm >> 4];
  const int rbase = (bm & 15)*128 + wr*64 + l16*4;
  float cs[4] = {0.f,0.f,0.f,0.f}, cs2[4] = {0.f,0.f,0.f,0.f};
  #pragma unroll
  for (int m=0;m<4;m++){
    #pragma unroll
    for (int r=0;r<4;r++){
      if (rbase + m*16 + r < pl){
        #pragma unroll
        for (int n=0;n<4;n++){
          float v = acc[m][n][r];
          cs[n] += v; cs2[n] += v*v;
        }
      }
    }
  }
  #pragma unroll
  for (int n=0;n<4;n++){
    cs[n]  += __shfl_xor(cs[n], 16, 64);  cs[n]  += __shfl_xor(cs[n], 32, 64);
    cs2[n] += __shfl_xor(cs2[n], 16, 64); cs2[n] += __shfl_xor(cs2[n], 32, 64);
  }
  float* lsum = (float*)&As[0][0];
  lsum[tid] = 0.f;
  __syncthreads();
  if (l16 == 0){
    #pragma unroll
    for (int n=0;n<4;n++){
      int col = wc*64 + n*16 + l15;
      atomicAdd(&lsum[col], cs[n]);
      atomicAdd(&lsum[128 + col], cs2[n]);
    }
  }
  __syncthreads();
  if (tid < 128)       atomicAdd(&sums[bn*128 + tid], lsum[tid]);
  else                 atomicAdd(&sums[NC + bn*128 + (tid-128)], lsum[tid]);
}

// ---------- final: coef2 in-block; y(bf16) -> relu(a*y+c) f32 ----------
__global__ __launch_bounds__(256) void final_kernel(const u16* __restrict__ Y,
                                                    float* __restrict__ O,
                                                    const float* __restrict__ sums,
                                                    const int* __restrict__ plen,
                                                    const float* __restrict__ g1,
                                                    const float* __restrict__ b1){
  __shared__ float cfl[OUTC*2];
  const int tid = threadIdx.x;
  {
    float cnt = 0.f;
    #pragma unroll
    for (int b=0;b<BB;b++) cnt += (float)plen[b];
    const float icnt = 1.f / cnt;
    for (int c = tid; c < OUTC; c += 256){
      float mean = sums[c] * icnt;
      float var  = fmaxf(sums[OUTC + c]*icnt - mean*mean, 0.f);
      float a = g1[c] * rsqrtf(var + BN_EPS);
      cfl[c] = a;
      cfl[OUTC + c] = b1[c] - mean*a;
    }
  }
  __syncthreads();
  const size_t base = (size_t)blockIdx.x * 128 * OUTC;   // 128 rows per block
  for (int i = tid; i < 128*OUTC/8; i += 256){
    size_t f = base + (size_t)i*8;
    int c = (int)(f % (size_t)OUTC);
    u32x4 v = *reinterpret_cast<const u32x4*>(Y + f);
    f32x4 o0, o1;
    #pragma unroll
    for (int j=0;j<4;j++){
      float lo = bf2f((u16)(v[j] & 0xffffu));
      float hi = bf2f((u16)(v[j] >> 16));
      float r0 = fmaxf(lo*cfl[c+2*j]   + cfl[OUTC+c+2*j],   0.f);
      float r1 = fmaxf(hi*cfl[c+2*j+1] + cfl[OUTC+c+2*j+1], 0.f);
      if (j < 2){ o0[2*j] = r0; o0[2*j+1] = r1; }
      else      { o1[2*(j-2)] = r0; o1[2*(j-2)+1] = r1; }
    }
    *reinterpret_cast<f32x4*>(O + f)     = o0;
    *reinterpret_cast<f32x4*>(O + f + 4) = o1;
  }
}

extern "C" void kernel_launch(void* const* d_in, const int* in_sizes, int n_in,
                              void* d_out, int out_size, void* d_ws, size_t ws_size,
                              hipStream_t stream){
  (void)in_sizes; (void)n_in; (void)out_size;
  const float* xyz1 = (const float*)d_in[0];
  const float* xyz2 = (const float*)d_in[1];
  const float* p1   = (const float*)d_in[2];
  const float* p2   = (const float*)d_in[3];
  const int*   plen = (const int*)d_in[4];
  const int*   elen = (const int*)d_in[5];
  const float* W0   = (const float*)d_in[7];
  const float* g0   = (const float*)d_in[8];
  const float* b0   = (const float*)d_in[9];
  const float* W1   = (const float*)d_in[10];
  const float* g1   = (const float*)d_in[11];
  const float* b1   = (const float*)d_in[12];
  float* out = (float*)d_out;
  char*  ws  = (char*)d_ws;

  u16*   W0b  = (u16*)  (ws + OFF_W0B);
  u16*   W1b  = (u16*)  (ws + OFF_W1B);
  int*   idxb = (int*)  (ws + OFF_IDX);
  float* wgtb = (float*)(ws + OFF_WGT);
  float* sum1 = (float*)(ws + OFF_SUM1);
  float* sum2 = (float*)(ws + OFF_SUM2);
  u16*   xcat = (u16*)  (ws + OFF_XCAT);   // reused as ybf after gemm1
  u16*   h1   = (u16*)  (ws + OFF_H1);
  const bool hasP2b = (ws_size >= NEED_P2B);
  u16*   p2b  = hasP2b ? (u16*)(ws + OFF_P2B) : nullptr;

  // conversions + stats zeroing (sums1|sums2 contiguous)
  {
    int maxT = hasP2b ? (BB*SS*DD) : (HID*CIN);
    cvtw_kernel<<<(maxT + 255)/256, 256, 0, stream>>>(W0, W1, p2, W0b, W1b, p2b, sum1);
  }
  knn_kernel<<<MROWS/4, 256, 0, stream>>>(xyz1, xyz2, elen, idxb, wgtb);
  if (hasP2b) xcat_kernel<true ><<<MROWS/4, 384, 0, stream>>>(p1, p2, p2b, idxb, wgtb, xcat);
  else        xcat_kernel<false><<<MROWS/4, 384, 0, stream>>>(p1, p2, p2b, idxb, wgtb, xcat);

  // GEMM1: h1 = xcat @ W0^T (bf16 out, stats fused)
  gemm1_kernel<<<6*256, 512, 0, stream>>>(xcat, W0b, h1, plen, sum1);

  // GEMM2: ybf = bf16( relu(bn1(h1)) @ W1^T ), coef1 in-block, stats fused
  gemm2_kernel<<<3*256, 256, 0, stream>>>(h1, W1b, xcat /*ybf*/, plen, sum2, sum1, g0, b0);

  // final: coef2 in-block, out = relu(a2*y + c2) in f32
  final_kernel<<<MROWS/128, 256, 0, stream>>>(xcat /*ybf*/, out, sum2, plen, g1, b1);
}

// Round 12
// 183.051 us; speedup vs baseline: 1.0277x; 1.0277x over previous
//
#include <hip/hip_runtime.h>
#include <cstdint>
#include <cstddef>

typedef unsigned short u16;
typedef __bf16 bf16x8 __attribute__((ext_vector_type(8)));
typedef float    f32x4 __attribute__((ext_vector_type(4)));
typedef unsigned int u32x4 __attribute__((ext_vector_type(4)));
typedef unsigned short u16x4 __attribute__((ext_vector_type(4)));

// ---------- problem constants ----------
constexpr int BB   = 16;
constexpr int NN   = 2048;
constexpr int SS   = 512;
constexpr int DD   = 384;   // D1 = D2 = 384
constexpr int CIN  = 768;   // D1+D2
constexpr int HID  = 768;
constexpr int OUTC = 384;
constexpr int MROWS = BB * NN; // 32768
constexpr float KNN_EPS = 1.1920929e-07f; // finfo(f32).eps
constexpr float BN_EPS  = 1e-5f;

// ---------- workspace layout (bytes) ----------
constexpr size_t OFF_W0B  = 0;                              // 768*768 bf16
constexpr size_t OFF_W1B  = OFF_W0B  + (size_t)HID*CIN*2;   // 384*768 bf16
constexpr size_t OFF_IDX  = OFF_W1B  + (size_t)OUTC*HID*2;  // MROWS*5 int
constexpr size_t OFF_WGT  = OFF_IDX  + (size_t)MROWS*5*4;
constexpr size_t OFF_SUM1 = OFF_WGT  + (size_t)MROWS*5*4;   // 768*2 f32
constexpr size_t OFF_SUM2 = OFF_SUM1 + (size_t)HID*2*4;     // 384*2 f32
constexpr size_t OFF_XCAT = OFF_SUM2 + (size_t)OUTC*2*4;    // MROWS*768 bf16 (reused as ybf)
constexpr size_t OFF_H1   = OFF_XCAT + (size_t)MROWS*CIN*2; // MROWS*768 bf16
constexpr size_t OFF_P2B  = OFF_H1   + (size_t)MROWS*HID*2; // 16*512*384 bf16 (optional)
constexpr size_t NEED_P2B = OFF_P2B  + (size_t)BB*SS*DD*2;

// ---------- helpers ----------
__device__ inline float bf2f(u16 u){ unsigned int i = ((unsigned int)u)<<16; float f; __builtin_memcpy(&f,&i,4); return f; }
__device__ inline u16 f2bf(float f){ unsigned int x; __builtin_memcpy(&x,&f,4);
  unsigned int r = (x + 0x7fffu + ((x>>16)&1u)) >> 16; return (u16)r; }

__device__ inline void async16(const void* g, void* l){
  __builtin_amdgcn_global_load_lds((const __attribute__((address_space(1))) void*)g,
                                   (__attribute__((address_space(3))) void*)l, 16, 0, 0);
}

// ---------- W f32 -> bf16, optional p2 -> bf16, zero stats ----------
__global__ void cvtw_kernel(const float* __restrict__ W0, const float* __restrict__ W1,
                            const float* __restrict__ p2,
                            u16* __restrict__ W0b, u16* __restrict__ W1b,
                            u16* __restrict__ p2b, float* __restrict__ sums){
  int t = blockIdx.x*256 + threadIdx.x;
  if (t < HID*CIN)  W0b[t] = f2bf(W0[t]);
  if (t < OUTC*HID) W1b[t] = f2bf(W1[t]);
  if (p2b != nullptr && t < BB*SS*DD) p2b[t] = f2bf(p2[t]);
  if (t < (HID + OUTC)*2) sums[t] = 0.f;
}

// ---------- KNN: one wave per query ----------
__global__ __launch_bounds__(256) void knn_kernel(const float* __restrict__ xyz1,
                                                  const float* __restrict__ xyz2,
                                                  const int* __restrict__ elens,
                                                  int* __restrict__ idxO, float* __restrict__ wO){
  __shared__ f32x4 sp[SS];
  const int tid = threadIdx.x;
  const int wv = tid >> 6, lane = tid & 63;
  const int wg = blockIdx.x*4 + wv;       // global wave id = query id
  const int b = wg >> 11;                 // 2048 queries per batch
  const int n = wg & (NN-1);
  for (int s = tid; s < SS; s += 256){
    float x = xyz2[((size_t)b*SS + s)*3 + 0];
    float y = xyz2[((size_t)b*SS + s)*3 + 1];
    float z = xyz2[((size_t)b*SS + s)*3 + 2];
    f32x4 v; v[0]=x; v[1]=y; v[2]=z; v[3]=x*x+y*y+z*z;
    sp[s]=v;
  }
  __syncthreads();
  const size_t qoff = ((size_t)b*NN + n)*3;
  const float qx = xyz1[qoff+0], qy = xyz1[qoff+1], qz = xyz1[qoff+2];
  const float qq = qx*qx + qy*qy + qz*qz;
  const int Sl = elens[b];

  float d0=1e30f,d1=1e30f,d2v=1e30f,d3=1e30f,d4=1e30f;
  int   i0=0,i1=0,i2=0,i3=0,i4=0;
  #pragma unroll
  for (int j=0;j<8;j++){
    const int s = lane + j*64;
    f32x4 v = sp[s];
    float d = (s < Sl) ? (qq + v[3] - 2.f*(qx*v[0] + qy*v[1] + qz*v[2])) : 1e30f;
    bool lt4=d<d4, lt3=d<d3, lt2=d<d2v, lt1=d<d1, lt0=d<d0;
    float nd4 = lt3 ? d3 : (lt4 ? d : d4); int ni4 = lt3 ? i3 : (lt4 ? s : i4);
    float nd3 = lt2 ? d2v: (lt3 ? d : d3); int ni3 = lt2 ? i2 : (lt3 ? s : i3);
    float nd2 = lt1 ? d1 : (lt2 ? d : d2v);int ni2 = lt1 ? i1 : (lt2 ? s : i2);
    float nd1 = lt0 ? d0 : (lt1 ? d : d1); int ni1 = lt0 ? i0 : (lt1 ? s : i1);
    float nd0 = lt0 ? d  : d0;             int ni0 = lt0 ? s  : i0;
    d4=nd4;i4=ni4; d3=nd3;i3=ni3; d2v=nd2;i2=ni2; d1=nd1;i1=ni1; d0=nd0;i0=ni0;
  }
  float outd[5]; int outi[5];
  #pragma unroll
  for (int r=0;r<5;r++){
    float bd = d0; int bs = i0;
    #pragma unroll
    for (int m=1;m<64;m<<=1){
      float od = __shfl_xor(bd, m, 64);
      int   os = __shfl_xor(bs, m, 64);
      if (od < bd || (od == bd && os < bs)){ bd = od; bs = os; }
    }
    outd[r]=bd; outi[r]=bs;
    if (d0 == bd && i0 == bs){ d0=d1;i0=i1; d1=d2v;i1=i2; d2v=d3;i2=i3; d3=d4;i3=i4; d4=1e30f;i4=0; }
  }
  if (lane == 0){
    float r0=1.f/(outd[0]+KNN_EPS), r1=1.f/(outd[1]+KNN_EPS), r2=1.f/(outd[2]+KNN_EPS),
          r3=1.f/(outd[3]+KNN_EPS), r4=1.f/(outd[4]+KNN_EPS);
    float inv = 1.f/(r0+r1+r2+r3+r4);
    size_t base = (size_t)wg*5;
    idxO[base+0]=outi[0]; idxO[base+1]=outi[1]; idxO[base+2]=outi[2]; idxO[base+3]=outi[3]; idxO[base+4]=outi[4];
    wO[base+0]=r0*inv; wO[base+1]=r1*inv; wO[base+2]=r2*inv; wO[base+3]=r3*inv; wO[base+4]=r4*inv;
  }
}

// ---------- xcat: 4 rows/block, 96 threads/row; gathers bf16 p2b (or f32 p2) ----------
template<bool BF16G>
__global__ __launch_bounds__(384) void xcat_kernel(const float* __restrict__ p1,
                                                   const float* __restrict__ p2,
                                                   const u16* __restrict__ p2b,
                                                   const int* __restrict__ idx,
                                                   const float* __restrict__ wgt,
                                                   u16* __restrict__ xcat){
  const int t = threadIdx.x;
  const int rloc = t / 96, c4 = t % 96;
  const int row = blockIdx.x*4 + rloc;
  const int b = row >> 11;
  const int c = c4*4;
  f32x4 v1 = *reinterpret_cast<const f32x4*>(p1 + (size_t)row*DD + c);
  size_t ib = (size_t)row*5;
  f32x4 acc = {0.f,0.f,0.f,0.f};
  #pragma unroll
  for (int k=0;k<5;k++){
    int id = idx[ib+k]; float w = wgt[ib+k];
    if (BF16G){
      u16x4 g = *reinterpret_cast<const u16x4*>(p2b + ((size_t)b*SS + id)*DD + c);
      #pragma unroll
      for (int j=0;j<4;j++) acc[j] += w * bf2f(g[j]);
    } else {
      f32x4 g = *reinterpret_cast<const f32x4*>(p2 + ((size_t)b*SS + id)*DD + c);
      #pragma unroll
      for (int j=0;j<4;j++) acc[j] += w * g[j];
    }
  }
  u16x4 o1, o2;
  #pragma unroll
  for (int j=0;j<4;j++){ o1[j] = f2bf(v1[j]); o2[j] = f2bf(acc[j]); }
  *reinterpret_cast<u16x4*>(xcat + (size_t)row*CIN + c)      = o1;
  *reinterpret_cast<u16x4*>(xcat + (size_t)row*CIN + DD + c) = o2;
}

// ---------- GEMM1: 128x128 tile, BK=64, 8 waves, 2-phase/tile, dist-2 dbuf ----------
// Per tile (buf cur=t&1): ph0 reads ALL A-frags (8) + B kh0 (2) -> barrier ->
// stageA(t+2,cur) [A fully read] -> 8 MFMA; ph1 reads B kh1 (2) -> barrier ->
// stageB(t+2,cur) -> 8 MFMA -> vmcnt(4) -> barrier. Swizzle: chunk k8'=k8^(row&7)
// (2-way banks); linear gload_lds dest, pre-swizzled global source, same XOR on reads.
__global__ __launch_bounds__(512, 4) void gemm1_kernel(const u16* __restrict__ A,
                                                       const u16* __restrict__ Bw,
                                                       u16* __restrict__ Cout,
                                                       const int* __restrict__ plen,
                                                       float* __restrict__ sums){
  constexpr int K   = CIN;         // 768
  constexpr int NC  = HID;         // 768
  constexpr int GX  = NC/128;      // 6
  constexpr int NT  = K/64;        // 12 tiles of BK=64
  constexpr int NWG = GX*256;      // 1536
  constexpr int CPX = NWG/8;
  __shared__ u16 Ash[2][128*64];   // 16KB each
  __shared__ u16 Bsh[2][128*64];
  const int tid  = threadIdx.x;
  const int lane = tid & 63, wv = tid >> 6;    // 8 waves
  const int wr = wv >> 2, wc = wv & 3;         // 2 x 4 wave grid, per-wave 64x32
  const int l15 = lane & 15, l16 = lane >> 4;

  const int logical = (blockIdx.x & 7)*CPX + (blockIdx.x >> 3);
  const int bn = logical % GX, bm = logical / GX;

  // staging: 1024 chunks(16B) per 128x64 tile; 2 chunks per thread (j=0: tid, j=1: 512+tid)
  // chunk ch -> LDS slot ch (linear); global k8 = (ch&7) ^ ((ch>>3)&7)
  int srowS[2]; int sk8S[2];
  #pragma unroll
  for (int j=0;j<2;j++){
    int ch = j*512 + tid;
    srowS[j] = ch >> 3;
    sk8S[j]  = (ch & 7) ^ ((ch >> 3) & 7);
  }
  const u16* gA0 = A  + (size_t)(bm*128 + srowS[0])*K + sk8S[0]*8;
  const u16* gA1 = A  + (size_t)(bm*128 + srowS[1])*K + sk8S[1]*8;
  const u16* gB0 = Bw + (size_t)(bn*128 + srowS[0])*K + sk8S[0]*8;
  const u16* gB1 = Bw + (size_t)(bn*128 + srowS[1])*K + sk8S[1]*8;
  const int dst0 = (wv*64)*16;            // wave-uniform LDS byte base, j=0
  const int dst1 = (512 + wv*64)*16;      // j=1

  auto stageA = [&](int tt, int bi){
    async16(gA0 + tt*64, (char*)&Ash[bi][0] + dst0);
    async16(gA1 + tt*64, (char*)&Ash[bi][0] + dst1);
  };
  auto stageB = [&](int tt, int bi){
    async16(gB0 + tt*64, (char*)&Bsh[bi][0] + dst0);
    async16(gB1 + tt*64, (char*)&Bsh[bi][0] + dst1);
  };

  // read offsets (u16 units): row, k-half kh, k-word l16:
  // slot = row*8 + ((kh*4 + l16) ^ (row&7)); off = slot*8
  int aoff[4][2], boff[2][2];
  #pragma unroll
  for (int m=0;m<4;m++){
    int r = wr*64 + m*16 + l15;
    #pragma unroll
    for (int kh=0;kh<2;kh++)
      aoff[m][kh] = (r*8 + (((kh*4 + l16) ^ (r & 7)))) * 8;
  }
  #pragma unroll
  for (int n=0;n<2;n++){
    int r = wc*32 + n*16 + l15;
    #pragma unroll
    for (int kh=0;kh<2;kh++)
      boff[n][kh] = (r*8 + (((kh*4 + l16) ^ (r & 7)))) * 8;
  }

  f32x4 acc[4][2] = {};

  // prologue: tiles 0,1 staged
  stageA(0,0); stageB(0,0); stageA(1,1); stageB(1,1);
  asm volatile("s_waitcnt vmcnt(4)" ::: "memory");   // tile 0 landed
  __builtin_amdgcn_s_barrier();
  __builtin_amdgcn_sched_barrier(0);

  for (int t=0; t<NT; ++t){
    const int cur = t & 1;
    const int tt = (t+2 < NT) ? (t+2) : (NT-1);   // clamped (same-data restage, safe)
    // ---- phase 0: ALL A frags + B kh0 ----
    bf16x8 af[4][2];
    #pragma unroll
    for (int m=0;m<4;m++){
      af[m][0] = *reinterpret_cast<const bf16x8*>(&Ash[cur][aoff[m][0]]);
      af[m][1] = *reinterpret_cast<const bf16x8*>(&Ash[cur][aoff[m][1]]);
    }
    bf16x8 b00 = *reinterpret_cast<const bf16x8*>(&Bsh[cur][boff[0][0]]);
    bf16x8 b10 = *reinterpret_cast<const bf16x8*>(&Bsh[cur][boff[1][0]]);
    asm volatile("s_waitcnt lgkmcnt(0)" ::: "memory");
    __builtin_amdgcn_s_barrier();                 // all waves' A (and B kh0) reads done
    __builtin_amdgcn_sched_barrier(0);
    stageA(tt, cur);                              // A[cur] fully read -> safe
    __builtin_amdgcn_s_setprio(1);
    acc[0][0] = __builtin_amdgcn_mfma_f32_16x16x32_bf16(af[0][0], b00, acc[0][0], 0,0,0);
    acc[1][0] = __builtin_amdgcn_mfma_f32_16x16x32_bf16(af[1][0], b00, acc[1][0], 0,0,0);
    acc[2][0] = __builtin_amdgcn_mfma_f32_16x16x32_bf16(af[2][0], b00, acc[2][0], 0,0,0);
    acc[3][0] = __builtin_amdgcn_mfma_f32_16x16x32_bf16(af[3][0], b00, acc[3][0], 0,0,0);
    acc[0][1] = __builtin_amdgcn_mfma_f32_16x16x32_bf16(af[0][0], b10, acc[0][1], 0,0,0);
    acc[1][1] = __builtin_amdgcn_mfma_f32_16x16x32_bf16(af[1][0], b10, acc[1][1], 0,0,0);
    acc[2][1] = __builtin_amdgcn_mfma_f32_16x16x32_bf16(af[2][0], b10, acc[2][1], 0,0,0);
    acc[3][1] = __builtin_amdgcn_mfma_f32_16x16x32_bf16(af[3][0], b10, acc[3][1], 0,0,0);
    __builtin_amdgcn_s_setprio(0);
    // ---- phase 1: B kh1 ----
    bf16x8 b01 = *reinterpret_cast<const bf16x8*>(&Bsh[cur][boff[0][1]]);
    bf16x8 b11 = *reinterpret_cast<const bf16x8*>(&Bsh[cur][boff[1][1]]);
    asm volatile("s_waitcnt lgkmcnt(0)" ::: "memory");
    __builtin_amdgcn_s_barrier();                 // all B reads of tile t done
    __builtin_amdgcn_sched_barrier(0);
    stageB(tt, cur);                              // B[cur] fully read -> safe
    __builtin_amdgcn_s_setprio(1);
    acc[0][0] = __builtin_amdgcn_mfma_f32_16x16x32_bf16(af[0][1], b01, acc[0][0], 0,0,0);
    acc[1][0] = __builtin_amdgcn_mfma_f32_16x16x32_bf16(af[1][1], b01, acc[1][0], 0,0,0);
    acc[2][0] = __builtin_amdgcn_mfma_f32_16x16x32_bf16(af[2][1], b01, acc[2][0], 0,0,0);
    acc[3][0] = __builtin_amdgcn_mfma_f32_16x16x32_bf16(af[3][1], b01, acc[3][0], 0,0,0);
    acc[0][1] = __builtin_amdgcn_mfma_f32_16x16x32_bf16(af[0][1], b11, acc[0][1], 0,0,0);
    acc[1][1] = __builtin_amdgcn_mfma_f32_16x16x32_bf16(af[1][1], b11, acc[1][1], 0,0,0);
    acc[2][1] = __builtin_amdgcn_mfma_f32_16x16x32_bf16(af[2][1], b11, acc[2][1], 0,0,0);
    acc[3][1] = __builtin_amdgcn_mfma_f32_16x16x32_bf16(af[3][1], b11, acc[3][1], 0,0,0);
    __builtin_amdgcn_s_setprio(0);
    asm volatile("s_waitcnt vmcnt(4)" ::: "memory");  // tile t+1 landed; t+2 in flight
    __builtin_amdgcn_s_barrier();
    __builtin_amdgcn_sched_barrier(0);
  }
  asm volatile("s_waitcnt vmcnt(0)" ::: "memory");
  __syncthreads();

  // ---- C write ----
  #pragma unroll
  for (int m=0;m<4;m++){
    int r0 = bm*128 + wr*64 + m*16 + l16*4;
    #pragma unroll
    for (int n=0;n<2;n++){
      int c = bn*128 + wc*32 + n*16 + l15;
      #pragma unroll
      for (int r=0;r<4;r++)
        Cout[(size_t)(r0+r)*NC + c] = f2bf(acc[m][n][r]);
    }
  }

  // ---- fused masked stats ----
  const int pl = plen[bm >> 4];
  const int rbase = (bm & 15)*128 + wr*64 + l16*4;
  float cs[2] = {0.f,0.f}, cs2[2] = {0.f,0.f};
  #pragma unroll
  for (int m=0;m<4;m++){
    #pragma unroll
    for (int r=0;r<4;r++){
      if (rbase + m*16 + r < pl){
        #pragma unroll
        for (int n=0;n<2;n++){
          float v = acc[m][n][r];
          cs[n] += v; cs2[n] += v*v;
        }
      }
    }
  }
  #pragma unroll
  for (int n=0;n<2;n++){
    cs[n]  += __shfl_xor(cs[n], 16, 64);  cs[n]  += __shfl_xor(cs[n], 32, 64);
    cs2[n] += __shfl_xor(cs2[n], 16, 64); cs2[n] += __shfl_xor(cs2[n], 32, 64);
  }
  float* lsum = (float*)&Ash[0][0];
  if (tid < 256) lsum[tid] = 0.f;
  __syncthreads();
  if (l16 == 0){
    #pragma unroll
    for (int n=0;n<2;n++){
      int col = wc*32 + n*16 + l15;
      atomicAdd(&lsum[col], cs[n]);
      atomicAdd(&lsum[128 + col], cs2[n]);
    }
  }
  __syncthreads();
  if (tid < 128)       atomicAdd(&sums[bn*128 + tid], lsum[tid]);
  else if (tid < 256)  atomicAdd(&sums[NC + bn*128 + (tid-128)], lsum[tid]);
}

// ---------- GEMM2: ring-buffered, coef1 computed in-block, BN1+ReLU fused on A, bf16 out ----------
__global__ __launch_bounds__(256) void gemm2_kernel(const u16* __restrict__ A,
                                                    const u16* __restrict__ Bw,
                                                    u16* __restrict__ Yout,
                                                    const int* __restrict__ plen,
                                                    float* __restrict__ sums,
                                                    const float* __restrict__ sum1,
                                                    const float* __restrict__ g0,
                                                    const float* __restrict__ b0){
  constexpr int GX = 3;
  constexpr int K  = HID;
  constexpr int NC = GX*128;       // 384
  constexpr int NSTEP = K/32;      // 24
  constexpr int NWG = GX*256;
  constexpr int CPX = NWG/8;
  __shared__ u16 As[2][128*32];
  __shared__ u16 Bs[3][128*32];
  __shared__ float cfl[HID*2];
  const int tid  = threadIdx.x;
  const int lane = tid & 63, wv = tid >> 6;
  const int wr = wv >> 1, wc = wv & 1;
  const int l15 = lane & 15, l16 = lane >> 4;
  const int sw  = (l15 >> 1) & 3;

  const int logical = (blockIdx.x & 7)*CPX + (blockIdx.x >> 3);
  const int bn = logical % GX, bm = logical / GX;

  int c8S[2], ldso[2];
  const u16* Ab[2]; const u16* Bb[2];
  #pragma unroll
  for (int j=0;j<2;j++){
    int ch = j*256 + wv*64 + lane;
    int row = ch >> 2;
    int c8 = (ch & 3) ^ ((ch >> 3) & 3);
    c8S[j] = c8;
    ldso[j] = (j*256 + wv*64)*16;
    Ab[j] = A  + (size_t)(bm*128 + row)*K + c8*8;
    Bb[j] = Bw + (size_t)(bn*128 + row)*K + c8*8;
  }

  auto stageB = [&](int nb, int kt){
    #pragma unroll
    for (int j=0;j<2;j++) async16(Bb[j] + kt*32, (char*)&Bs[nb][0] + ldso[j]);
  };
  u32x4 hv0, hv1;
  auto loadA = [&](int kt){
    hv0 = *reinterpret_cast<const u32x4*>(Ab[0] + kt*32);
    hv1 = *reinterpret_cast<const u32x4*>(Ab[1] + kt*32);
  };
  auto bnwrite = [&](int nb, int kt){
    #pragma unroll
    for (int j=0;j<2;j++){
      const int k0 = kt*32 + c8S[j]*8;
      float av[8], bv[8];
      *reinterpret_cast<f32x4*>(av)   = *reinterpret_cast<const f32x4*>(cfl + k0);
      *reinterpret_cast<f32x4*>(av+4) = *reinterpret_cast<const f32x4*>(cfl + k0 + 4);
      *reinterpret_cast<f32x4*>(bv)   = *reinterpret_cast<const f32x4*>(cfl + K + k0);
      *reinterpret_cast<f32x4*>(bv+4) = *reinterpret_cast<const f32x4*>(cfl + K + k0 + 4);
      u32x4 v = j ? hv1 : hv0; u32x4 o;
      #pragma unroll
      for (int q=0;q<4;q++){
        float lo = bf2f((u16)(v[q] & 0xffffu));
        float hi = bf2f((u16)(v[q] >> 16));
        lo = fmaxf(lo*av[2*q]   + bv[2*q],   0.f);
        hi = fmaxf(hi*av[2*q+1] + bv[2*q+1], 0.f);
        o[q] = (unsigned int)f2bf(lo) | ((unsigned int)f2bf(hi) << 16);
      }
      *reinterpret_cast<u32x4*>((char*)&As[nb][0] + ldso[j] + lane*16) = o;
    }
  };

  f32x4 acc[4][4] = {};

  // issue tile-0 loads, then compute coef1 into LDS while DMA is in flight
  loadA(0);
  __builtin_amdgcn_sched_barrier(0);
  stageB(0, 0); stageB(1, 1);
  {
    float cnt = 0.f;
    #pragma unroll
    for (int b=0;b<BB;b++) cnt += (float)plen[b];
    const float icnt = 1.f / cnt;
    for (int c = tid; c < HID; c += 256){
      float mean = sum1[c] * icnt;
      float var  = fmaxf(sum1[HID + c]*icnt - mean*mean, 0.f);
      float a = g0[c] * rsqrtf(var + BN_EPS);
      cfl[c] = a;
      cfl[HID + c] = b0[c] - mean*a;
    }
  }
  __syncthreads();
  bnwrite(0, 0);
  asm volatile("s_waitcnt vmcnt(2) lgkmcnt(0)" ::: "memory");
  __builtin_amdgcn_s_barrier();

  int rb = 0, wb = 2;
  for (int kt=0; kt<NSTEP; ++kt){
    const bool pf1 = (kt+1 < NSTEP), pf2 = (kt+2 < NSTEP);
    if (pf1) loadA(kt+1);
    __builtin_amdgcn_sched_barrier(0);
    if (pf2) stageB(wb, kt+2);

    bf16x8 af[4], bfr[4];
    const int aslot = kt & 1;
    #pragma unroll
    for (int m=0;m<4;m++){
      int r = wr*64 + m*16 + l15;
      af[m] = *reinterpret_cast<const bf16x8*>(&As[aslot][r*32 + ((l16 ^ sw) << 3)]);
    }
    #pragma unroll
    for (int n=0;n<4;n++){
      int c = wc*64 + n*16 + l15;
      bfr[n] = *reinterpret_cast<const bf16x8*>(&Bs[rb][c*32 + ((l16 ^ sw) << 3)]);
    }
    #pragma unroll
    for (int m=0;m<4;m++)
      #pragma unroll
      for (int n=0;n<4;n++)
        acc[m][n] = __builtin_amdgcn_mfma_f32_16x16x32_bf16(af[m], bfr[n], acc[m][n], 0, 0, 0);

    if (pf1) bnwrite((kt+1)&1, kt+1);

    if (pf1){
      if (pf2) asm volatile("s_waitcnt vmcnt(2) lgkmcnt(0)" ::: "memory");
      else     asm volatile("s_waitcnt vmcnt(0) lgkmcnt(0)" ::: "memory");
      __builtin_amdgcn_s_barrier();
    }
    rb = (rb==2) ? 0 : rb+1;
    wb = (wb==2) ? 0 : wb+1;
  }

  // ---- C write (bf16 y) ----
  #pragma unroll
  for (int m=0;m<4;m++){
    int r0 = bm*128 + wr*64 + m*16 + l16*4;
    #pragma unroll
    for (int n=0;n<4;n++){
      int c = bn*128 + wc*64 + n*16 + l15;
      #pragma unroll
      for (int r=0;r<4;r++)
        Yout[(size_t)(r0+r)*NC + c] = f2bf(acc[m][n][r]);
    }
  }

  // ---- masked stats (f32-exact) ----
  const int pl = plen[bm >> 4];
  const int rbase = (bm & 15)*128 + wr*64 + l16*4;
  float cs[4] = {0.f,0.f,0.f,0.f}, cs2[4] = {0.f,0.f,0.f,0.f};
  #pragma unroll
  for (int m=0;m<4;m++){
    #pragma unroll
    for (int r=0;r<4;r++){
      if (rbase + m*16 + r < pl){
        #pragma unroll
        for (int n=0;n<4;n++){
          float v = acc[m][n][r];
          cs[n] += v; cs2[n] += v*v;
        }
      }
    }
  }
  #pragma unroll
  for (int n=0;n<4;n++){
    cs[n]  += __shfl_xor(cs[n], 16, 64);  cs[n]  += __shfl_xor(cs[n], 32, 64);
    cs2[n] += __shfl_xor(cs2[n], 16, 64); cs2[n] += __shfl_xor(cs2[n], 32, 64);
  }
  float* lsum = (float*)&As[0][0];
  lsum[tid] = 0.f;
  __syncthreads();
  if (l16 == 0){
    #pragma unroll
    for (int n=0;n<4;n++){
      int col = wc*64 + n*16 + l15;
      atomicAdd(&lsum[col], cs[n]);
      atomicAdd(&lsum[128 + col], cs2[n]);
    }
  }
  __syncthreads();
  if (tid < 128)       atomicAdd(&sums[bn*128 + tid], lsum[tid]);
  else                 atomicAdd(&sums[NC + bn*128 + (tid-128)], lsum[tid]);
}

// ---------- final: coef2 in-block; y(bf16) -> relu(a*y+c) f32 ----------
__global__ __launch_bounds__(256) void final_kernel(const u16* __restrict__ Y,
                                                    float* __restrict__ O,
                                                    const float* __restrict__ sums,
                                                    const int* __restrict__ plen,
                                                    const float* __restrict__ g1,
                                                    const float* __restrict__ b1){
  __shared__ float cfl[OUTC*2];
  const int tid = threadIdx.x;
  {
    float cnt = 0.f;
    #pragma unroll
    for (int b=0;b<BB;b++) cnt += (float)plen[b];
    const float icnt = 1.f / cnt;
    for (int c = tid; c < OUTC; c += 256){
      float mean = sums[c] * icnt;
      float var  = fmaxf(sums[OUTC + c]*icnt - mean*mean, 0.f);
      float a = g1[c] * rsqrtf(var + BN_EPS);
      cfl[c] = a;
      cfl[OUTC + c] = b1[c] - mean*a;
    }
  }
  __syncthreads();
  const size_t base = (size_t)blockIdx.x * 128 * OUTC;   // 128 rows per block
  for (int i = tid; i < 128*OUTC/8; i += 256){
    size_t f = base + (size_t)i*8;
    int c = (int)(f % (size_t)OUTC);
    u32x4 v = *reinterpret_cast<const u32x4*>(Y + f);
    f32x4 o0, o1;
    #pragma unroll
    for (int j=0;j<4;j++){
      float lo = bf2f((u16)(v[j] & 0xffffu));
      float hi = bf2f((u16)(v[j] >> 16));
      float r0 = fmaxf(lo*cfl[c+2*j]   + cfl[OUTC+c+2*j],   0.f);
      float r1 = fmaxf(hi*cfl[c+2*j+1] + cfl[OUTC+c+2*j+1], 0.f);
      if (j < 2){ o0[2*j] = r0; o0[2*j+1] = r1; }
      else      { o1[2*(j-2)] = r0; o1[2*(j-2)+1] = r1; }
    }
    *reinterpret_cast<f32x4*>(O + f)     = o0;
    *reinterpret_cast<f32x4*>(O + f + 4) = o1;
  }
}

extern "C" void kernel_launch(void* const* d_in, const int* in_sizes, int n_in,
                              void* d_out, int out_size, void* d_ws, size_t ws_size,
                              hipStream_t stream){
  (void)in_sizes; (void)n_in; (void)out_size;
  const float* xyz1 = (const float*)d_in[0];
  const float* xyz2 = (const float*)d_in[1];
  const float* p1   = (const float*)d_in[2];
  const float* p2   = (const float*)d_in[3];
  const int*   plen = (const int*)d_in[4];
  const int*   elen = (const int*)d_in[5];
  const float* W0   = (const float*)d_in[7];
  const float* g0   = (const float*)d_in[8];
  const float* b0   = (const float*)d_in[9];
  const float* W1   = (const float*)d_in[10];
  const float* g1   = (const float*)d_in[11];
  const float* b1   = (const float*)d_in[12];
  float* out = (float*)d_out;
  char*  ws  = (char*)d_ws;

  u16*   W0b  = (u16*)  (ws + OFF_W0B);
  u16*   W1b  = (u16*)  (ws + OFF_W1B);
  int*   idxb = (int*)  (ws + OFF_IDX);
  float* wgtb = (float*)(ws + OFF_WGT);
  float* sum1 = (float*)(ws + OFF_SUM1);
  float* sum2 = (float*)(ws + OFF_SUM2);
  u16*   xcat = (u16*)  (ws + OFF_XCAT);   // reused as ybf after gemm1
  u16*   h1   = (u16*)  (ws + OFF_H1);
  const bool hasP2b = (ws_size >= NEED_P2B);
  u16*   p2b  = hasP2b ? (u16*)(ws + OFF_P2B) : nullptr;

  // conversions + stats zeroing (sums1|sums2 contiguous)
  {
    int maxT = hasP2b ? (BB*SS*DD) : (HID*CIN);
    cvtw_kernel<<<(maxT + 255)/256, 256, 0, stream>>>(W0, W1, p2, W0b, W1b, p2b, sum1);
  }
  knn_kernel<<<MROWS/4, 256, 0, stream>>>(xyz1, xyz2, elen, idxb, wgtb);
  if (hasP2b) xcat_kernel<true ><<<MROWS/4, 384, 0, stream>>>(p1, p2, p2b, idxb, wgtb, xcat);
  else        xcat_kernel<false><<<MROWS/4, 384, 0, stream>>>(p1, p2, p2b, idxb, wgtb, xcat);

  // GEMM1: h1 = xcat @ W0^T (bf16 out, stats fused) — BK=64 variant
  gemm1_kernel<<<6*256, 512, 0, stream>>>(xcat, W0b, h1, plen, sum1);

  // GEMM2: ybf = bf16( relu(bn1(h1)) @ W1^T ), coef1 in-block, stats fused
  gemm2_kernel<<<3*256, 256, 0, stream>>>(h1, W1b, xcat /*ybf*/, plen, sum2, sum1, g0, b0);

  // final: coef2 in-block, out = relu(a2*y + c2) in f32
  final_kernel<<<MROWS/128, 256, 0, stream>>>(xcat /*ybf*/, out, sum2, plen, g1, b1);
}

// Round 13
// 172.052 us; speedup vs baseline: 1.0934x; 1.0639x over previous
//
#include <hip/hip_runtime.h>
#include <cstdint>
#include <cstddef>

typedef unsigned short u16;
typedef __bf16 bf16x8 __attribute__((ext_vector_type(8)));
typedef float    f32x4 __attribute__((ext_vector_type(4)));
typedef unsigned int u32x4 __attribute__((ext_vector_type(4)));
typedef unsigned short u16x4 __attribute__((ext_vector_type(4)));

// ---------- problem constants ----------
constexpr int BB   = 16;
constexpr int NN   = 2048;
constexpr int SS   = 512;
constexpr int DD   = 384;   // D1 = D2 = 384
constexpr int CIN  = 768;   // D1+D2
constexpr int HID  = 768;
constexpr int OUTC = 384;
constexpr int MROWS = BB * NN; // 32768
constexpr float KNN_EPS = 1.1920929e-07f; // finfo(f32).eps
constexpr float BN_EPS  = 1e-5f;

// ---------- workspace layout (bytes) ----------
constexpr size_t OFF_W0B  = 0;                              // 768*768 bf16
constexpr size_t OFF_W1B  = OFF_W0B  + (size_t)HID*CIN*2;   // 384*768 bf16
constexpr size_t OFF_IDX  = OFF_W1B  + (size_t)OUTC*HID*2;  // MROWS*5 int
constexpr size_t OFF_WGT  = OFF_IDX  + (size_t)MROWS*5*4;
constexpr size_t OFF_SUM1 = OFF_WGT  + (size_t)MROWS*5*4;   // 768*2 f32
constexpr size_t OFF_SUM2 = OFF_SUM1 + (size_t)HID*2*4;     // 384*2 f32
constexpr size_t OFF_XCAT = OFF_SUM2 + (size_t)OUTC*2*4;    // MROWS*768 bf16 (reused as ybf)
constexpr size_t OFF_H1   = OFF_XCAT + (size_t)MROWS*CIN*2; // MROWS*768 bf16
constexpr size_t OFF_P2B  = OFF_H1   + (size_t)MROWS*HID*2; // 16*512*384 bf16 (optional)
constexpr size_t NEED_P2B = OFF_P2B  + (size_t)BB*SS*DD*2;

// ---------- helpers ----------
__device__ inline float bf2f(u16 u){ unsigned int i = ((unsigned int)u)<<16; float f; __builtin_memcpy(&f,&i,4); return f; }
__device__ inline u16 f2bf(float f){ unsigned int x; __builtin_memcpy(&x,&f,4);
  unsigned int r = (x + 0x7fffu + ((x>>16)&1u)) >> 16; return (u16)r; }

__device__ inline void async16(const void* g, void* l){
  __builtin_amdgcn_global_load_lds((const __attribute__((address_space(1))) void*)g,
                                   (__attribute__((address_space(3))) void*)l, 16, 0, 0);
}

// ---------- W f32 -> bf16, optional p2 -> bf16, zero stats ----------
__global__ void cvtw_kernel(const float* __restrict__ W0, const float* __restrict__ W1,
                            const float* __restrict__ p2,
                            u16* __restrict__ W0b, u16* __restrict__ W1b,
                            u16* __restrict__ p2b, float* __restrict__ sums){
  int t = blockIdx.x*256 + threadIdx.x;
  if (t < HID*CIN)  W0b[t] = f2bf(W0[t]);
  if (t < OUTC*HID) W1b[t] = f2bf(W1[t]);
  if (p2b != nullptr && t < BB*SS*DD) p2b[t] = f2bf(p2[t]);
  if (t < (HID + OUTC)*2) sums[t] = 0.f;
}

// ---------- KNN: one wave per query ----------
__global__ __launch_bounds__(256) void knn_kernel(const float* __restrict__ xyz1,
                                                  const float* __restrict__ xyz2,
                                                  const int* __restrict__ elens,
                                                  int* __restrict__ idxO, float* __restrict__ wO){
  __shared__ f32x4 sp[SS];
  const int tid = threadIdx.x;
  const int wv = tid >> 6, lane = tid & 63;
  const int wg = blockIdx.x*4 + wv;       // global wave id = query id
  const int b = wg >> 11;                 // 2048 queries per batch
  const int n = wg & (NN-1);
  for (int s = tid; s < SS; s += 256){
    float x = xyz2[((size_t)b*SS + s)*3 + 0];
    float y = xyz2[((size_t)b*SS + s)*3 + 1];
    float z = xyz2[((size_t)b*SS + s)*3 + 2];
    f32x4 v; v[0]=x; v[1]=y; v[2]=z; v[3]=x*x+y*y+z*z;
    sp[s]=v;
  }
  __syncthreads();
  const size_t qoff = ((size_t)b*NN + n)*3;
  const float qx = xyz1[qoff+0], qy = xyz1[qoff+1], qz = xyz1[qoff+2];
  const float qq = qx*qx + qy*qy + qz*qz;
  const int Sl = elens[b];

  float d0=1e30f,d1=1e30f,d2v=1e30f,d3=1e30f,d4=1e30f;
  int   i0=0,i1=0,i2=0,i3=0,i4=0;
  #pragma unroll
  for (int j=0;j<8;j++){
    const int s = lane + j*64;
    f32x4 v = sp[s];
    float d = (s < Sl) ? (qq + v[3] - 2.f*(qx*v[0] + qy*v[1] + qz*v[2])) : 1e30f;
    bool lt4=d<d4, lt3=d<d3, lt2=d<d2v, lt1=d<d1, lt0=d<d0;
    float nd4 = lt3 ? d3 : (lt4 ? d : d4); int ni4 = lt3 ? i3 : (lt4 ? s : i4);
    float nd3 = lt2 ? d2v: (lt3 ? d : d3); int ni3 = lt2 ? i2 : (lt3 ? s : i3);
    float nd2 = lt1 ? d1 : (lt2 ? d : d2v);int ni2 = lt1 ? i1 : (lt2 ? s : i2);
    float nd1 = lt0 ? d0 : (lt1 ? d : d1); int ni1 = lt0 ? i0 : (lt1 ? s : i1);
    float nd0 = lt0 ? d  : d0;             int ni0 = lt0 ? s  : i0;
    d4=nd4;i4=ni4; d3=nd3;i3=ni3; d2v=nd2;i2=ni2; d1=nd1;i1=ni1; d0=nd0;i0=ni0;
  }
  float outd[5]; int outi[5];
  #pragma unroll
  for (int r=0;r<5;r++){
    float bd = d0; int bs = i0;
    #pragma unroll
    for (int m=1;m<64;m<<=1){
      float od = __shfl_xor(bd, m, 64);
      int   os = __shfl_xor(bs, m, 64);
      if (od < bd || (od == bd && os < bs)){ bd = od; bs = os; }
    }
    outd[r]=bd; outi[r]=bs;
    if (d0 == bd && i0 == bs){ d0=d1;i0=i1; d1=d2v;i1=i2; d2v=d3;i2=i3; d3=d4;i3=i4; d4=1e30f;i4=0; }
  }
  if (lane == 0){
    float r0=1.f/(outd[0]+KNN_EPS), r1=1.f/(outd[1]+KNN_EPS), r2=1.f/(outd[2]+KNN_EPS),
          r3=1.f/(outd[3]+KNN_EPS), r4=1.f/(outd[4]+KNN_EPS);
    float inv = 1.f/(r0+r1+r2+r3+r4);
    size_t base = (size_t)wg*5;
    idxO[base+0]=outi[0]; idxO[base+1]=outi[1]; idxO[base+2]=outi[2]; idxO[base+3]=outi[3]; idxO[base+4]=outi[4];
    wO[base+0]=r0*inv; wO[base+1]=r1*inv; wO[base+2]=r2*inv; wO[base+3]=r3*inv; wO[base+4]=r4*inv;
  }
}

// ---------- xcat: 4 rows/block, 96 threads/row; gathers bf16 p2b (or f32 p2) ----------
template<bool BF16G>
__global__ __launch_bounds__(384) void xcat_kernel(const float* __restrict__ p1,
                                                   const float* __restrict__ p2,
                                                   const u16* __restrict__ p2b,
                                                   const int* __restrict__ idx,
                                                   const float* __restrict__ wgt,
                                                   u16* __restrict__ xcat){
  const int t = threadIdx.x;
  const int rloc = t / 96, c4 = t % 96;
  const int row = blockIdx.x*4 + rloc;
  const int b = row >> 11;
  const int c = c4*4;
  f32x4 v1 = *reinterpret_cast<const f32x4*>(p1 + (size_t)row*DD + c);
  size_t ib = (size_t)row*5;
  f32x4 acc = {0.f,0.f,0.f,0.f};
  #pragma unroll
  for (int k=0;k<5;k++){
    int id = idx[ib+k]; float w = wgt[ib+k];
    if (BF16G){
      u16x4 g = *reinterpret_cast<const u16x4*>(p2b + ((size_t)b*SS + id)*DD + c);
      #pragma unroll
      for (int j=0;j<4;j++) acc[j] += w * bf2f(g[j]);
    } else {
      f32x4 g = *reinterpret_cast<const f32x4*>(p2 + ((size_t)b*SS + id)*DD + c);
      #pragma unroll
      for (int j=0;j<4;j++) acc[j] += w * g[j];
    }
  }
  u16x4 o1, o2;
  #pragma unroll
  for (int j=0;j<4;j++){ o1[j] = f2bf(v1[j]); o2[j] = f2bf(acc[j]); }
  *reinterpret_cast<u16x4*>(xcat + (size_t)row*CIN + c)      = o1;
  *reinterpret_cast<u16x4*>(xcat + (size_t)row*CIN + DD + c) = o2;
}

// ---------- GEMM1: 128x128 tile, BK=64, 8 waves, 2-phase/tile, dist-2 dbuf (R12 champion) ----------
__global__ __launch_bounds__(512, 4) void gemm1_kernel(const u16* __restrict__ A,
                                                       const u16* __restrict__ Bw,
                                                       u16* __restrict__ Cout,
                                                       const int* __restrict__ plen,
                                                       float* __restrict__ sums){
  constexpr int K   = CIN;         // 768
  constexpr int NC  = HID;         // 768
  constexpr int GX  = NC/128;      // 6
  constexpr int NT  = K/64;        // 12 tiles of BK=64
  constexpr int NWG = GX*256;      // 1536
  constexpr int CPX = NWG/8;
  __shared__ u16 Ash[2][128*64];   // 16KB each
  __shared__ u16 Bsh[2][128*64];
  const int tid  = threadIdx.x;
  const int lane = tid & 63, wv = tid >> 6;    // 8 waves
  const int wr = wv >> 2, wc = wv & 3;         // 2 x 4 wave grid, per-wave 64x32
  const int l15 = lane & 15, l16 = lane >> 4;

  const int logical = (blockIdx.x & 7)*CPX + (blockIdx.x >> 3);
  const int bn = logical % GX, bm = logical / GX;

  int srowS[2]; int sk8S[2];
  #pragma unroll
  for (int j=0;j<2;j++){
    int ch = j*512 + tid;
    srowS[j] = ch >> 3;
    sk8S[j]  = (ch & 7) ^ ((ch >> 3) & 7);
  }
  const u16* gA0 = A  + (size_t)(bm*128 + srowS[0])*K + sk8S[0]*8;
  const u16* gA1 = A  + (size_t)(bm*128 + srowS[1])*K + sk8S[1]*8;
  const u16* gB0 = Bw + (size_t)(bn*128 + srowS[0])*K + sk8S[0]*8;
  const u16* gB1 = Bw + (size_t)(bn*128 + srowS[1])*K + sk8S[1]*8;
  const int dst0 = (wv*64)*16;
  const int dst1 = (512 + wv*64)*16;

  auto stageA = [&](int tt, int bi){
    async16(gA0 + tt*64, (char*)&Ash[bi][0] + dst0);
    async16(gA1 + tt*64, (char*)&Ash[bi][0] + dst1);
  };
  auto stageB = [&](int tt, int bi){
    async16(gB0 + tt*64, (char*)&Bsh[bi][0] + dst0);
    async16(gB1 + tt*64, (char*)&Bsh[bi][0] + dst1);
  };

  int aoff[4][2], boff[2][2];
  #pragma unroll
  for (int m=0;m<4;m++){
    int r = wr*64 + m*16 + l15;
    #pragma unroll
    for (int kh=0;kh<2;kh++)
      aoff[m][kh] = (r*8 + (((kh*4 + l16) ^ (r & 7)))) * 8;
  }
  #pragma unroll
  for (int n=0;n<2;n++){
    int r = wc*32 + n*16 + l15;
    #pragma unroll
    for (int kh=0;kh<2;kh++)
      boff[n][kh] = (r*8 + (((kh*4 + l16) ^ (r & 7)))) * 8;
  }

  f32x4 acc[4][2] = {};

  stageA(0,0); stageB(0,0); stageA(1,1); stageB(1,1);
  asm volatile("s_waitcnt vmcnt(4)" ::: "memory");
  __builtin_amdgcn_s_barrier();
  __builtin_amdgcn_sched_barrier(0);

  for (int t=0; t<NT; ++t){
    const int cur = t & 1;
    const int tt = (t+2 < NT) ? (t+2) : (NT-1);
    bf16x8 af[4][2];
    #pragma unroll
    for (int m=0;m<4;m++){
      af[m][0] = *reinterpret_cast<const bf16x8*>(&Ash[cur][aoff[m][0]]);
      af[m][1] = *reinterpret_cast<const bf16x8*>(&Ash[cur][aoff[m][1]]);
    }
    bf16x8 b00 = *reinterpret_cast<const bf16x8*>(&Bsh[cur][boff[0][0]]);
    bf16x8 b10 = *reinterpret_cast<const bf16x8*>(&Bsh[cur][boff[1][0]]);
    asm volatile("s_waitcnt lgkmcnt(0)" ::: "memory");
    __builtin_amdgcn_s_barrier();
    __builtin_amdgcn_sched_barrier(0);
    stageA(tt, cur);
    __builtin_amdgcn_s_setprio(1);
    acc[0][0] = __builtin_amdgcn_mfma_f32_16x16x32_bf16(af[0][0], b00, acc[0][0], 0,0,0);
    acc[1][0] = __builtin_amdgcn_mfma_f32_16x16x32_bf16(af[1][0], b00, acc[1][0], 0,0,0);
    acc[2][0] = __builtin_amdgcn_mfma_f32_16x16x32_bf16(af[2][0], b00, acc[2][0], 0,0,0);
    acc[3][0] = __builtin_amdgcn_mfma_f32_16x16x32_bf16(af[3][0], b00, acc[3][0], 0,0,0);
    acc[0][1] = __builtin_amdgcn_mfma_f32_16x16x32_bf16(af[0][0], b10, acc[0][1], 0,0,0);
    acc[1][1] = __builtin_amdgcn_mfma_f32_16x16x32_bf16(af[1][0], b10, acc[1][1], 0,0,0);
    acc[2][1] = __builtin_amdgcn_mfma_f32_16x16x32_bf16(af[2][0], b10, acc[2][1], 0,0,0);
    acc[3][1] = __builtin_amdgcn_mfma_f32_16x16x32_bf16(af[3][0], b10, acc[3][1], 0,0,0);
    __builtin_amdgcn_s_setprio(0);
    bf16x8 b01 = *reinterpret_cast<const bf16x8*>(&Bsh[cur][boff[0][1]]);
    bf16x8 b11 = *reinterpret_cast<const bf16x8*>(&Bsh[cur][boff[1][1]]);
    asm volatile("s_waitcnt lgkmcnt(0)" ::: "memory");
    __builtin_amdgcn_s_barrier();
    __builtin_amdgcn_sched_barrier(0);
    stageB(tt, cur);
    __builtin_amdgcn_s_setprio(1);
    acc[0][0] = __builtin_amdgcn_mfma_f32_16x16x32_bf16(af[0][1], b01, acc[0][0], 0,0,0);
    acc[1][0] = __builtin_amdgcn_mfma_f32_16x16x32_bf16(af[1][1], b01, acc[1][0], 0,0,0);
    acc[2][0] = __builtin_amdgcn_mfma_f32_16x16x32_bf16(af[2][1], b01, acc[2][0], 0,0,0);
    acc[3][0] = __builtin_amdgcn_mfma_f32_16x16x32_bf16(af[3][1], b01, acc[3][0], 0,0,0);
    acc[0][1] = __builtin_amdgcn_mfma_f32_16x16x32_bf16(af[0][1], b11, acc[0][1], 0,0,0);
    acc[1][1] = __builtin_amdgcn_mfma_f32_16x16x32_bf16(af[1][1], b11, acc[1][1], 0,0,0);
    acc[2][1] = __builtin_amdgcn_mfma_f32_16x16x32_bf16(af[2][1], b11, acc[2][1], 0,0,0);
    acc[3][1] = __builtin_amdgcn_mfma_f32_16x16x32_bf16(af[3][1], b11, acc[3][1], 0,0,0);
    __builtin_amdgcn_s_setprio(0);
    asm volatile("s_waitcnt vmcnt(4)" ::: "memory");
    __builtin_amdgcn_s_barrier();
    __builtin_amdgcn_sched_barrier(0);
  }
  asm volatile("s_waitcnt vmcnt(0)" ::: "memory");
  __syncthreads();

  #pragma unroll
  for (int m=0;m<4;m++){
    int r0 = bm*128 + wr*64 + m*16 + l16*4;
    #pragma unroll
    for (int n=0;n<2;n++){
      int c = bn*128 + wc*32 + n*16 + l15;
      #pragma unroll
      for (int r=0;r<4;r++)
        Cout[(size_t)(r0+r)*NC + c] = f2bf(acc[m][n][r]);
    }
  }

  const int pl = plen[bm >> 4];
  const int rbase = (bm & 15)*128 + wr*64 + l16*4;
  float cs[2] = {0.f,0.f}, cs2[2] = {0.f,0.f};
  #pragma unroll
  for (int m=0;m<4;m++){
    #pragma unroll
    for (int r=0;r<4;r++){
      if (rbase + m*16 + r < pl){
        #pragma unroll
        for (int n=0;n<2;n++){
          float v = acc[m][n][r];
          cs[n] += v; cs2[n] += v*v;
        }
      }
    }
  }
  #pragma unroll
  for (int n=0;n<2;n++){
    cs[n]  += __shfl_xor(cs[n], 16, 64);  cs[n]  += __shfl_xor(cs[n], 32, 64);
    cs2[n] += __shfl_xor(cs2[n], 16, 64); cs2[n] += __shfl_xor(cs2[n], 32, 64);
  }
  float* lsum = (float*)&Ash[0][0];
  if (tid < 256) lsum[tid] = 0.f;
  __syncthreads();
  if (l16 == 0){
    #pragma unroll
    for (int n=0;n<2;n++){
      int col = wc*32 + n*16 + l15;
      atomicAdd(&lsum[col], cs[n]);
      atomicAdd(&lsum[128 + col], cs2[n]);
    }
  }
  __syncthreads();
  if (tid < 128)       atomicAdd(&sums[bn*128 + tid], lsum[tid]);
  else if (tid < 256)  atomicAdd(&sums[NC + bn*128 + (tid-128)], lsum[tid]);
}

// ---------- GEMM2: BK=64, 8 waves, 2-phase/tile; coef1 in-block; BN1+ReLU fused on A (reg-staged) ----------
// A: per thread 2x16B chunks loaded to regs (loadA(t+1) at tile start), BN applied,
// ds_write to As[nxt] after MFMA (As[nxt] consumed at tile t-1; safe). B: gload_lds
// dist-2 into Bsh[cur] after ph1 barrier (B fully read). Swizzle identical to gemm1.
__global__ __launch_bounds__(512) void gemm2_kernel(const u16* __restrict__ A,
                                                    const u16* __restrict__ Bw,
                                                    u16* __restrict__ Yout,
                                                    const int* __restrict__ plen,
                                                    float* __restrict__ sums,
                                                    const float* __restrict__ sum1,
                                                    const float* __restrict__ g0,
                                                    const float* __restrict__ b0){
  constexpr int K   = HID;         // 768
  constexpr int NC  = OUTC;        // 384
  constexpr int GX  = NC/128;      // 3
  constexpr int NT  = K/64;        // 12
  constexpr int NWG = (MROWS/128)*GX; // 768
  constexpr int CPX = NWG/8;
  __shared__ u16 Ash[2][128*64];
  __shared__ u16 Bsh[2][128*64];
  __shared__ float cfl[HID*2];
  const int tid  = threadIdx.x;
  const int lane = tid & 63, wv = tid >> 6;
  const int wr = wv >> 2, wc = wv & 3;         // per-wave 64x32
  const int l15 = lane & 15, l16 = lane >> 4;

  const int logical = (blockIdx.x & 7)*CPX + (blockIdx.x >> 3);
  const int bn = logical % GX, bm = logical / GX;

  int srowS[2]; int sk8S[2];
  #pragma unroll
  for (int j=0;j<2;j++){
    int ch = j*512 + tid;
    srowS[j] = ch >> 3;
    sk8S[j]  = (ch & 7) ^ ((ch >> 3) & 7);
  }
  const u16* gA0 = A  + (size_t)(bm*128 + srowS[0])*K + sk8S[0]*8;
  const u16* gA1 = A  + (size_t)(bm*128 + srowS[1])*K + sk8S[1]*8;
  const u16* gB0 = Bw + (size_t)(bn*128 + srowS[0])*K + sk8S[0]*8;
  const u16* gB1 = Bw + (size_t)(bn*128 + srowS[1])*K + sk8S[1]*8;
  const int dst0 = (wv*64)*16;
  const int dst1 = (512 + wv*64)*16;

  auto stageB = [&](int tt, int bi){
    async16(gB0 + tt*64, (char*)&Bsh[bi][0] + dst0);
    async16(gB1 + tt*64, (char*)&Bsh[bi][0] + dst1);
  };
  u32x4 hv0, hv1;
  auto loadA = [&](int tt){
    hv0 = *reinterpret_cast<const u32x4*>(gA0 + tt*64);
    hv1 = *reinterpret_cast<const u32x4*>(gA1 + tt*64);
  };
  auto bnwrite = [&](int tt, int bi){
    #pragma unroll
    for (int j=0;j<2;j++){
      const int k0 = tt*64 + sk8S[j]*8;
      float av[8], bv[8];
      *reinterpret_cast<f32x4*>(av)   = *reinterpret_cast<const f32x4*>(cfl + k0);
      *reinterpret_cast<f32x4*>(av+4) = *reinterpret_cast<const f32x4*>(cfl + k0 + 4);
      *reinterpret_cast<f32x4*>(bv)   = *reinterpret_cast<const f32x4*>(cfl + K + k0);
      *reinterpret_cast<f32x4*>(bv+4) = *reinterpret_cast<const f32x4*>(cfl + K + k0 + 4);
      u32x4 v = j ? hv1 : hv0; u32x4 o;
      #pragma unroll
      for (int q=0;q<4;q++){
        float lo = bf2f((u16)(v[q] & 0xffffu));
        float hi = bf2f((u16)(v[q] >> 16));
        lo = fmaxf(lo*av[2*q]   + bv[2*q],   0.f);
        hi = fmaxf(hi*av[2*q+1] + bv[2*q+1], 0.f);
        o[q] = (unsigned int)f2bf(lo) | ((unsigned int)f2bf(hi) << 16);
      }
      *reinterpret_cast<u32x4*>((char*)&Ash[bi][0] + (j*512 + tid)*16) = o;
    }
  };

  int aoff[4][2], boff[2][2];
  #pragma unroll
  for (int m=0;m<4;m++){
    int r = wr*64 + m*16 + l15;
    #pragma unroll
    for (int kh=0;kh<2;kh++)
      aoff[m][kh] = (r*8 + (((kh*4 + l16) ^ (r & 7)))) * 8;
  }
  #pragma unroll
  for (int n=0;n<2;n++){
    int r = wc*32 + n*16 + l15;
    #pragma unroll
    for (int kh=0;kh<2;kh++)
      boff[n][kh] = (r*8 + (((kh*4 + l16) ^ (r & 7)))) * 8;
  }

  f32x4 acc[4][2] = {};

  // prologue: A0 regs, B0/B1 DMA, coef1 while in flight, then bnwrite A0
  loadA(0);
  __builtin_amdgcn_sched_barrier(0);
  stageB(0, 0); stageB(1, 1);
  {
    float cnt = 0.f;
    #pragma unroll
    for (int b=0;b<BB;b++) cnt += (float)plen[b];
    const float icnt = 1.f / cnt;
    for (int c = tid; c < HID; c += 512){
      float mean = sum1[c] * icnt;
      float var  = fmaxf(sum1[HID + c]*icnt - mean*mean, 0.f);
      float a = g0[c] * rsqrtf(var + BN_EPS);
      cfl[c] = a;
      cfl[HID + c] = b0[c] - mean*a;
    }
  }
  __syncthreads();                      // cfl visible
  bnwrite(0, 0);                        // waits loadA(0) via vmcnt
  asm volatile("s_waitcnt vmcnt(2) lgkmcnt(0)" ::: "memory");  // B0 landed; B1 in flight
  __builtin_amdgcn_s_barrier();
  __builtin_amdgcn_sched_barrier(0);

  for (int t=0; t<NT; ++t){
    const int cur = t & 1, nxt = cur ^ 1;
    const bool pf1 = (t+1 < NT), pf2 = (t+2 < NT);
    if (pf1) loadA(t+1);
    __builtin_amdgcn_sched_barrier(0);
    // ---- phase 0: ALL A frags + B kh0 ----
    bf16x8 af[4][2];
    #pragma unroll
    for (int m=0;m<4;m++){
      af[m][0] = *reinterpret_cast<const bf16x8*>(&Ash[cur][aoff[m][0]]);
      af[m][1] = *reinterpret_cast<const bf16x8*>(&Ash[cur][aoff[m][1]]);
    }
    bf16x8 b00 = *reinterpret_cast<const bf16x8*>(&Bsh[cur][boff[0][0]]);
    bf16x8 b10 = *reinterpret_cast<const bf16x8*>(&Bsh[cur][boff[1][0]]);
    asm volatile("s_waitcnt lgkmcnt(0)" ::: "memory");
    __builtin_amdgcn_s_barrier();
    __builtin_amdgcn_sched_barrier(0);
    __builtin_amdgcn_s_setprio(1);
    acc[0][0] = __builtin_amdgcn_mfma_f32_16x16x32_bf16(af[0][0], b00, acc[0][0], 0,0,0);
    acc[1][0] = __builtin_amdgcn_mfma_f32_16x16x32_bf16(af[1][0], b00, acc[1][0], 0,0,0);
    acc[2][0] = __builtin_amdgcn_mfma_f32_16x16x32_bf16(af[2][0], b00, acc[2][0], 0,0,0);
    acc[3][0] = __builtin_amdgcn_mfma_f32_16x16x32_bf16(af[3][0], b00, acc[3][0], 0,0,0);
    acc[0][1] = __builtin_amdgcn_mfma_f32_16x16x32_bf16(af[0][0], b10, acc[0][1], 0,0,0);
    acc[1][1] = __builtin_amdgcn_mfma_f32_16x16x32_bf16(af[1][0], b10, acc[1][1], 0,0,0);
    acc[2][1] = __builtin_amdgcn_mfma_f32_16x16x32_bf16(af[2][0], b10, acc[2][1], 0,0,0);
    acc[3][1] = __builtin_amdgcn_mfma_f32_16x16x32_bf16(af[3][0], b10, acc[3][1], 0,0,0);
    __builtin_amdgcn_s_setprio(0);
    // ---- phase 1: B kh1 ----
    bf16x8 b01 = *reinterpret_cast<const bf16x8*>(&Bsh[cur][boff[0][1]]);
    bf16x8 b11 = *reinterpret_cast<const bf16x8*>(&Bsh[cur][boff[1][1]]);
    asm volatile("s_waitcnt lgkmcnt(0)" ::: "memory");
    __builtin_amdgcn_s_barrier();                 // B[cur] fully read
    __builtin_amdgcn_sched_barrier(0);
    if (pf2) stageB(t+2, cur);
    __builtin_amdgcn_s_setprio(1);
    acc[0][0] = __builtin_amdgcn_mfma_f32_16x16x32_bf16(af[0][1], b01, acc[0][0], 0,0,0);
    acc[1][0] = __builtin_amdgcn_mfma_f32_16x16x32_bf16(af[1][1], b01, acc[1][0], 0,0,0);
    acc[2][0] = __builtin_amdgcn_mfma_f32_16x16x32_bf16(af[2][1], b01, acc[2][0], 0,0,0);
    acc[3][0] = __builtin_amdgcn_mfma_f32_16x16x32_bf16(af[3][1], b01, acc[3][0], 0,0,0);
    acc[0][1] = __builtin_amdgcn_mfma_f32_16x16x32_bf16(af[0][1], b11, acc[0][1], 0,0,0);
    acc[1][1] = __builtin_amdgcn_mfma_f32_16x16x32_bf16(af[1][1], b11, acc[1][1], 0,0,0);
    acc[2][1] = __builtin_amdgcn_mfma_f32_16x16x32_bf16(af[2][1], b11, acc[2][1], 0,0,0);
    acc[3][1] = __builtin_amdgcn_mfma_f32_16x16x32_bf16(af[3][1], b11, acc[3][1], 0,0,0);
    __builtin_amdgcn_s_setprio(0);
    if (pf1) bnwrite(t+1, nxt);                   // As[nxt] consumed at t-1; safe
    if (pf2) asm volatile("s_waitcnt vmcnt(2) lgkmcnt(0)" ::: "memory");
    else     asm volatile("s_waitcnt vmcnt(0) lgkmcnt(0)" ::: "memory");
    __builtin_amdgcn_s_barrier();
    __builtin_amdgcn_sched_barrier(0);
  }
  __syncthreads();

  // ---- C write (bf16 y) ----
  #pragma unroll
  for (int m=0;m<4;m++){
    int r0 = bm*128 + wr*64 + m*16 + l16*4;
    #pragma unroll
    for (int n=0;n<2;n++){
      int c = bn*128 + wc*32 + n*16 + l15;
      #pragma unroll
      for (int r=0;r<4;r++)
        Yout[(size_t)(r0+r)*NC + c] = f2bf(acc[m][n][r]);
    }
  }

  // ---- masked stats (f32-exact) ----
  const int pl = plen[bm >> 4];
  const int rbase = (bm & 15)*128 + wr*64 + l16*4;
  float cs[2] = {0.f,0.f}, cs2[2] = {0.f,0.f};
  #pragma unroll
  for (int m=0;m<4;m++){
    #pragma unroll
    for (int r=0;r<4;r++){
      if (rbase + m*16 + r < pl){
        #pragma unroll
        for (int n=0;n<2;n++){
          float v = acc[m][n][r];
          cs[n] += v; cs2[n] += v*v;
        }
      }
    }
  }
  #pragma unroll
  for (int n=0;n<2;n++){
    cs[n]  += __shfl_xor(cs[n], 16, 64);  cs[n]  += __shfl_xor(cs[n], 32, 64);
    cs2[n] += __shfl_xor(cs2[n], 16, 64); cs2[n] += __shfl_xor(cs2[n], 32, 64);
  }
  float* lsum = (float*)&Ash[0][0];
  if (tid < 256) lsum[tid] = 0.f;
  __syncthreads();
  if (l16 == 0){
    #pragma unroll
    for (int n=0;n<2;n++){
      int col = wc*32 + n*16 + l15;
      atomicAdd(&lsum[col], cs[n]);
      atomicAdd(&lsum[128 + col], cs2[n]);
    }
  }
  __syncthreads();
  if (tid < 128)       atomicAdd(&sums[bn*128 + tid], lsum[tid]);
  else if (tid < 256)  atomicAdd(&sums[NC + bn*128 + (tid-128)], lsum[tid]);
}

// ---------- final: coef2 in-block; y(bf16) -> relu(a*y+c) f32 ----------
__global__ __launch_bounds__(256) void final_kernel(const u16* __restrict__ Y,
                                                    float* __restrict__ O,
                                                    const float* __restrict__ sums,
                                                    const int* __restrict__ plen,
                                                    const float* __restrict__ g1,
                                                    const float* __restrict__ b1){
  __shared__ float cfl[OUTC*2];
  const int tid = threadIdx.x;
  {
    float cnt = 0.f;
    #pragma unroll
    for (int b=0;b<BB;b++) cnt += (float)plen[b];
    const float icnt = 1.f / cnt;
    for (int c = tid; c < OUTC; c += 256){
      float mean = sums[c] * icnt;
      float var  = fmaxf(sums[OUTC + c]*icnt - mean*mean, 0.f);
      float a = g1[c] * rsqrtf(var + BN_EPS);
      cfl[c] = a;
      cfl[OUTC + c] = b1[c] - mean*a;
    }
  }
  __syncthreads();
  const size_t base = (size_t)blockIdx.x * 128 * OUTC;   // 128 rows per block
  for (int i = tid; i < 128*OUTC/8; i += 256){
    size_t f = base + (size_t)i*8;
    int c = (int)(f % (size_t)OUTC);
    u32x4 v = *reinterpret_cast<const u32x4*>(Y + f);
    f32x4 o0, o1;
    #pragma unroll
    for (int j=0;j<4;j++){
      float lo = bf2f((u16)(v[j] & 0xffffu));
      float hi = bf2f((u16)(v[j] >> 16));
      float r0 = fmaxf(lo*cfl[c+2*j]   + cfl[OUTC+c+2*j],   0.f);
      float r1 = fmaxf(hi*cfl[c+2*j+1] + cfl[OUTC+c+2*j+1], 0.f);
      if (j < 2){ o0[2*j] = r0; o0[2*j+1] = r1; }
      else      { o1[2*(j-2)] = r0; o1[2*(j-2)+1] = r1; }
    }
    *reinterpret_cast<f32x4*>(O + f)     = o0;
    *reinterpret_cast<f32x4*>(O + f + 4) = o1;
  }
}

extern "C" void kernel_launch(void* const* d_in, const int* in_sizes, int n_in,
                              void* d_out, int out_size, void* d_ws, size_t ws_size,
                              hipStream_t stream){
  (void)in_sizes; (void)n_in; (void)out_size;
  const float* xyz1 = (const float*)d_in[0];
  const float* xyz2 = (const float*)d_in[1];
  const float* p1   = (const float*)d_in[2];
  const float* p2   = (const float*)d_in[3];
  const int*   plen = (const int*)d_in[4];
  const int*   elen = (const int*)d_in[5];
  const float* W0   = (const float*)d_in[7];
  const float* g0   = (const float*)d_in[8];
  const float* b0   = (const float*)d_in[9];
  const float* W1   = (const float*)d_in[10];
  const float* g1   = (const float*)d_in[11];
  const float* b1   = (const float*)d_in[12];
  float* out = (float*)d_out;
  char*  ws  = (char*)d_ws;

  u16*   W0b  = (u16*)  (ws + OFF_W0B);
  u16*   W1b  = (u16*)  (ws + OFF_W1B);
  int*   idxb = (int*)  (ws + OFF_IDX);
  float* wgtb = (float*)(ws + OFF_WGT);
  float* sum1 = (float*)(ws + OFF_SUM1);
  float* sum2 = (float*)(ws + OFF_SUM2);
  u16*   xcat = (u16*)  (ws + OFF_XCAT);   // reused as ybf after gemm1
  u16*   h1   = (u16*)  (ws + OFF_H1);
  const bool hasP2b = (ws_size >= NEED_P2B);
  u16*   p2b  = hasP2b ? (u16*)(ws + OFF_P2B) : nullptr;

  // conversions + stats zeroing (sums1|sums2 contiguous)
  {
    int maxT = hasP2b ? (BB*SS*DD) : (HID*CIN);
    cvtw_kernel<<<(maxT + 255)/256, 256, 0, stream>>>(W0, W1, p2, W0b, W1b, p2b, sum1);
  }
  knn_kernel<<<MROWS/4, 256, 0, stream>>>(xyz1, xyz2, elen, idxb, wgtb);
  if (hasP2b) xcat_kernel<true ><<<MROWS/4, 384, 0, stream>>>(p1, p2, p2b, idxb, wgtb, xcat);
  else        xcat_kernel<false><<<MROWS/4, 384, 0, stream>>>(p1, p2, p2b, idxb, wgtb, xcat);

  // GEMM1: h1 = xcat @ W0^T (bf16 out, stats fused) — BK=64
  gemm1_kernel<<<6*256, 512, 0, stream>>>(xcat, W0b, h1, plen, sum1);

  // GEMM2: ybf = bf16( relu(bn1(h1)) @ W1^T ), BK=64, coef1 in-block, stats fused
  gemm2_kernel<<<3*256, 512, 0, stream>>>(h1, W1b, xcat /*ybf*/, plen, sum2, sum1, g0, b0);

  // final: coef2 in-block, out = relu(a2*y + c2) in f32
  final_kernel<<<MROWS/128, 256, 0, stream>>>(xcat /*ybf*/, out, sum2, plen, g1, b1);
}